// Round 7
// baseline (152.797 us; speedup 1.0000x reference)
//
#include <hip/hip_runtime.h>
#include <math.h>

#define NB 2
#define NH 8
#define BHN 16
#define SS 160
#define DD 64

typedef __attribute__((ext_vector_type(8))) short bf16x8;
typedef __attribute__((ext_vector_type(4))) float f32x4;

// split a pair of fp32 into packed bf16 (hi, lo); lo captures the residual.
__device__ __forceinline__ uint2 splitpair(float a0, float a1) {
    unsigned u0 = __float_as_uint(a0), u1 = __float_as_uint(a1);
    unsigned hi = (u0 >> 16) | (u1 & 0xffff0000u);
    float r0 = a0 - __uint_as_float(u0 & 0xffff0000u);
    float r1 = a1 - __uint_as_float(u1 & 0xffff0000u);
    unsigned v0 = __float_as_uint(r0), v1 = __float_as_uint(r1);
    unsigned lo = (v0 >> 16) | (v1 & 0xffff0000u);
    return make_uint2(hi, lo);
}

// ============================ PHASE 1 ============================
// Block = (bh, q-chunk 32, s-chunk SLEN). grid = 16*5*(160/SLEN).
// Per fixed s: scores[q32, t160] = (Q ⊙ k1[s,:]) x k2^T, 3-term bf16 hi/lo
// MFMA; k2 fragments hoisted to registers. Q pre-scaled by log2(e) so the
// softmax exp is a bare v_exp_f32 (exp2). m=0 softmax (scores*log2e < ~66,
// fits fp32 range). Outputs (all exclusive, plain stores, NO atomics):
//   A1g[bh][q][s]  row-marginal exp-sums over t   (this block's s-slice)
//   A2p[blk][32 q][160 t]  col-marginal partial   (this block's s-chunk sum)
template <int SLEN>
__global__ __launch_bounds__(256, 3) void tritt_p1(
    const float* __restrict__ q,  const float* __restrict__ k1,
    const float* __restrict__ k2, float* __restrict__ A1g,
    float* __restrict__ A2p)
{
    constexpr int NSC = SS / SLEN;
    __shared__ __align__(16) char sm[40960 + SLEN * 256 + SLEN * 128];
    char*  k2hB  = sm;                          // bf16 hi [160 t][8 blk][16B]
    char*  k2lB  = sm + 20480;                  // bf16 lo
    float* k1buf = (float*)(sm + 40960);        // [SLEN s][64 h]
    float* A1buf = (float*)(sm + 40960 + SLEN * 256); // [SLEN s][32 q]

    const int tid = threadIdx.x;
    const int blk = blockIdx.x;                 // = (bh*5+qc)*NSC + sc
    const int bh  = blk / (5 * NSC);
    const int rem = blk % (5 * NSC);
    const int qc  = rem / NSC, sc = rem % NSC;
    const size_t base = (size_t)bh * SS * DD;

    // ---- stage k2 (all 160 t) as hi/lo bf16, 16B-block swizzled by t&7 ----
    const float4* k2f = (const float4*)(k2 + base);
    #pragma unroll
    for (int it = 0; it < 5; ++it) {
        int f = tid + 256 * it;                 // t = f>>3, 16B-block o = f&7
        int t = f >> 3, o = f & 7;
        float4 x0 = k2f[t * 16 + 2 * o];
        float4 x1 = k2f[t * 16 + 2 * o + 1];
        uint2 p0 = splitpair(x0.x, x0.y);
        uint2 p1 = splitpair(x0.z, x0.w);
        uint2 p2 = splitpair(x1.x, x1.y);
        uint2 p3 = splitpair(x1.z, x1.w);
        int off = t * 128 + ((o ^ (t & 7)) * 16);
        *(uint4*)(k2hB + off) = make_uint4(p0.x, p1.x, p2.x, p3.x);
        *(uint4*)(k2lB + off) = make_uint4(p0.y, p1.y, p2.y, p3.y);
    }
    // ---- stage k1 chunk (SLEN rows, fp32) ----
    {
        const float4* k1f4 = (const float4*)(k1 + base) + sc * (SLEN * 16);
        float4* dst = (float4*)k1buf;
        dst[tid] = k1f4[tid];
        if (SLEN == 32) dst[tid + 256] = k1f4[tid + 256];
    }
    #pragma unroll
    for (int i = tid; i < SLEN * 8; i += 256)
        ((float4*)A1buf)[i] = make_float4(0.f, 0.f, 0.f, 0.f);

    const int lane = tid & 63, wid = tid >> 6;
    const int mt = wid & 1, nh = wid >> 1;
    const int n16 = lane & 15, quad = lane >> 4;

    // Q rows (fp32, registers, pre-scaled by log2e): n16 -> q row, quad -> h-octet
    const float* qrow = q + base + (size_t)(qc * 32 + mt * 16 + n16) * DD + quad * 8;
    const float LOG2E = 1.4426950408889634f;
    float Qf[2][8];
    #pragma unroll
    for (int ks = 0; ks < 2; ++ks) {
        float4 a = *(const float4*)(qrow + 32 * ks);
        float4 b = *(const float4*)(qrow + 32 * ks + 4);
        Qf[ks][0] = a.x * LOG2E; Qf[ks][1] = a.y * LOG2E;
        Qf[ks][2] = a.z * LOG2E; Qf[ks][3] = a.w * LOG2E;
        Qf[ks][4] = b.x * LOG2E; Qf[ks][5] = b.y * LOG2E;
        Qf[ks][6] = b.z * LOG2E; Qf[ks][7] = b.w * LOG2E;
    }
    __syncthreads();

    // ---- hoist ALL k2 fragments (hi+lo) into registers (s-invariant) ----
    const int trow = nh * 80 + n16;
    const int swz  = n16 & 7;
    const char* bb0 = k2hB + trow * 128 + ((quad) ^ swz) * 16;
    const char* bb1 = k2hB + trow * 128 + ((4 + quad) ^ swz) * 16;
    const char* lb0 = k2lB + trow * 128 + ((quad) ^ swz) * 16;
    const char* lb1 = k2lB + trow * 128 + ((4 + quad) ^ swz) * 16;
    bf16x8 BH0[5], BH1[5], BL0[5], BL1[5];
    #pragma unroll
    for (int j = 0; j < 5; ++j) {
        BH0[j] = *(const bf16x8*)(bb0 + 2048 * j);
        BH1[j] = *(const bf16x8*)(bb1 + 2048 * j);
        BL0[j] = *(const bf16x8*)(lb0 + 2048 * j);
        BL1[j] = *(const bf16x8*)(lb1 + 2048 * j);
    }

    f32x4 A2acc[5];
    #pragma unroll
    for (int j = 0; j < 5; ++j) A2acc[j] = (f32x4){0.f, 0.f, 0.f, 0.f};
    const f32x4 zero4 = (f32x4){0.f, 0.f, 0.f, 0.f};

    // ---- s-loop: build A = Q ⊙ k1[s,:], 30 MFMAs, exp2, accumulate ----
    #pragma unroll 2
    for (int s = 0; s < SLEN; ++s) {
        const float* k1row = k1buf + s * 64 + quad * 8;
        uint4 AH[2], AL[2];
        #pragma unroll
        for (int ks = 0; ks < 2; ++ks) {
            float4 a = *(const float4*)(k1row + 32 * ks);
            float4 b = *(const float4*)(k1row + 32 * ks + 4);
            uint2 p0 = splitpair(Qf[ks][0] * a.x, Qf[ks][1] * a.y);
            uint2 p1 = splitpair(Qf[ks][2] * a.z, Qf[ks][3] * a.w);
            uint2 p2 = splitpair(Qf[ks][4] * b.x, Qf[ks][5] * b.y);
            uint2 p3 = splitpair(Qf[ks][6] * b.z, Qf[ks][7] * b.w);
            AH[ks] = make_uint4(p0.x, p1.x, p2.x, p3.x);
            AL[ks] = make_uint4(p0.y, p1.y, p2.y, p3.y);
        }
        bf16x8 ah0 = *(bf16x8*)&AH[0], al0 = *(bf16x8*)&AL[0];
        bf16x8 ah1 = *(bf16x8*)&AH[1], al1 = *(bf16x8*)&AL[1];

        float rsum[4] = {0.f, 0.f, 0.f, 0.f};
        #pragma unroll
        for (int j = 0; j < 5; ++j) {
            f32x4 a = __builtin_amdgcn_mfma_f32_16x16x32_bf16(ah0, BH0[j], zero4, 0, 0, 0);
            a = __builtin_amdgcn_mfma_f32_16x16x32_bf16(al0, BH0[j], a, 0, 0, 0);
            a = __builtin_amdgcn_mfma_f32_16x16x32_bf16(ah0, BL0[j], a, 0, 0, 0);
            a = __builtin_amdgcn_mfma_f32_16x16x32_bf16(ah1, BH1[j], a, 0, 0, 0);
            a = __builtin_amdgcn_mfma_f32_16x16x32_bf16(al1, BH1[j], a, 0, 0, 0);
            a = __builtin_amdgcn_mfma_f32_16x16x32_bf16(ah1, BL1[j], a, 0, 0, 0);
            #pragma unroll
            for (int r = 0; r < 4; ++r) {
                float e = exp2f(a[r]);          // scores pre-scaled by log2e
                A2acc[j][r] += e;
                rsum[r] += e;
            }
        }
        #pragma unroll
        for (int r = 0; r < 4; ++r) {
            float v = rsum[r];
            v += __shfl_xor(v, 1, 64); v += __shfl_xor(v, 2, 64);
            v += __shfl_xor(v, 4, 64); v += __shfl_xor(v, 8, 64);
            if (n16 == 0)
                atomicAdd(&A1buf[s * 32 + mt * 16 + quad * 4 + r], v);
        }
    }
    __syncthreads();

    // ---- write A1 slice (exclusive, coalesced-ish small) ----
    {
        float* dst = A1g + (size_t)bh * 25600 + sc * SLEN;
        if (SLEN == 16) {
            int qi = tid >> 3, s2 = (tid & 7) * 2;
            float2 w = make_float2(A1buf[s2 * 32 + qi], A1buf[(s2 + 1) * 32 + qi]);
            *(float2*)(dst + (size_t)(qc * 32 + qi) * SS + s2) = w;
        } else {
            int qi = tid >> 3, s4 = (tid & 7) * 4;
            float4 w = make_float4(A1buf[s4 * 32 + qi], A1buf[(s4 + 1) * 32 + qi],
                                   A1buf[(s4 + 2) * 32 + qi], A1buf[(s4 + 3) * 32 + qi]);
            *(float4*)(dst + (size_t)(qc * 32 + qi) * SS + s4) = w;
        }
    }
    // ---- write A2 partial straight from registers (exclusive, coalesced) ----
    {
        float* pb = A2p + (size_t)blk * 5120;
        #pragma unroll
        for (int j = 0; j < 5; ++j)
            #pragma unroll
            for (int r = 0; r < 4; ++r)
                pb[(mt * 16 + quad * 4 + r) * SS + nh * 80 + j * 16 + n16] = A2acc[j][r];
    }
}

// ============================ PHASE 2 ============================
// grid 640 x 128. Wave handles 2 queries: reduce NSC A2 partials, stage
// A1/A2 rows in LDS (per-wave exclusive -> no barriers), then
// z[q,d] = (A1·v1 + A2·v2)/l once; lse = log(l). All loads coalesced.
template <int NSC>
__global__ __launch_bounds__(128) void tritt_p2(
    const float* __restrict__ v1, const float* __restrict__ v2,
    const float* __restrict__ A1g, const float* __restrict__ A2p,
    float* __restrict__ out)
{
    __shared__ float A1s[4][SS];
    __shared__ float A2s[4][SS];

    const int tid = threadIdx.x;
    const int lane = tid & 63, wid = tid >> 6;
    const int blk = blockIdx.x;
    const int bh = blk / 40, qg = blk % 40;
    const int q0 = qg * 4 + wid * 2;            // even; q0,q0+1 share qc
    const int qc = q0 >> 5, ql = q0 & 31;
    const size_t base = (size_t)bh * SS * DD;

    float l[2] = {0.f, 0.f};
    #pragma unroll
    for (int k = 0; k < 2; ++k) {
        const float* row = A1g + (size_t)bh * 25600 + (size_t)(q0 + k) * SS;
        #pragma unroll
        for (int i = 0; i < 3; ++i) {
            int idx = lane + 64 * i;
            if (idx < SS) {
                float v = row[idx];
                A1s[wid * 2 + k][idx] = v;
                l[k] += v;
            }
        }
    }
    #pragma unroll
    for (int k = 0; k < 2; ++k) {
        float a[3] = {0.f, 0.f, 0.f};
        for (int p = 0; p < NSC; ++p) {
            const float* pb = A2p + (size_t)((bh * 5 + qc) * NSC + p) * 5120
                            + (size_t)(ql + k) * SS;
            #pragma unroll
            for (int i = 0; i < 3; ++i) {
                int idx = lane + 64 * i;
                if (idx < SS) a[i] += pb[idx];
            }
        }
        #pragma unroll
        for (int i = 0; i < 3; ++i) {
            int idx = lane + 64 * i;
            if (idx < SS) A2s[wid * 2 + k][idx] = a[i];
        }
    }
    #pragma unroll
    for (int k = 0; k < 2; ++k)
        #pragma unroll
        for (int off = 32; off; off >>= 1) l[k] += __shfl_xor(l[k], off, 64);

    const float* A10 = A1s[wid * 2], *A11 = A1s[wid * 2 + 1];
    const float* A20 = A2s[wid * 2], *A21 = A2s[wid * 2 + 1];
    const float* v1p = v1 + base, *v2p = v2 + base;
    float z0 = 0.f, z1 = 0.f;
    #pragma unroll 8
    for (int s = 0; s < SS; ++s) {
        float vv = v1p[s * DD + lane];
        z0 = fmaf(A10[s], vv, z0);
        z1 = fmaf(A11[s], vv, z1);
    }
    #pragma unroll 8
    for (int t = 0; t < SS; ++t) {
        float vv = v2p[t * DD + lane];
        z0 = fmaf(A20[t], vv, z0);
        z1 = fmaf(A21[t], vv, z1);
    }
    out[base + (size_t)q0 * DD + lane]       = z0 / l[0];
    out[base + (size_t)(q0 + 1) * DD + lane] = z1 / l[1];
    if (lane == 0) {
        out[(size_t)BHN * SS * DD + bh * SS + q0]     = __logf(l[0]);
        out[(size_t)BHN * SS * DD + bh * SS + q0 + 1] = __logf(l[1]);
    }
}

// ==================== FALLBACK (proven R2, ~74us) ====================
__global__ __launch_bounds__(256, 2) void tritt_fb(
    const float* __restrict__ q,  const float* __restrict__ k1,
    const float* __restrict__ k2, const float* __restrict__ v1,
    const float* __restrict__ v2, float* __restrict__ out)
{
    __shared__ __align__(16) char sm[81920];
    const int tid = threadIdx.x;
    const int blk = blockIdx.x;
    const int bh  = blk / SS;
    const int qi  = blk % SS;
    const size_t base = (size_t)bh * SS * DD;

    const float4* k1f = (const float4*)(k1 + base);
    const float4* k2f = (const float4*)(k2 + base);
    const float4* qf  = (const float4*)(q + base + (size_t)qi * DD);

    #pragma unroll
    for (int it = 0; it < 5; ++it) {
        int f = tid + 256 * it;
        int s = f >> 3, g = f & 7;
        int fg = s * 16 + g * 2;
        float4 x0 = k1f[fg], x1 = k1f[fg + 1];
        float4 y0 = k2f[fg], y1 = k2f[fg + 1];
        float4 q0 = qf[g * 2], q1 = qf[g * 2 + 1];
        uint2 pa0 = splitpair(x0.x * q0.x, x0.y * q0.y);
        uint2 pa1 = splitpair(x0.z * q0.z, x0.w * q0.w);
        uint2 pa2 = splitpair(x1.x * q1.x, x1.y * q1.y);
        uint2 pa3 = splitpair(x1.z * q1.z, x1.w * q1.w);
        uint2 pb0 = splitpair(y0.x, y0.y);
        uint2 pb1 = splitpair(y0.z, y0.w);
        uint2 pb2 = splitpair(y1.x, y1.y);
        uint2 pb3 = splitpair(y1.z, y1.w);
        int off = s * 128 + ((g ^ (s & 7)) * 16);
        *(uint4*)(sm + off)         = make_uint4(pa0.x, pa1.x, pa2.x, pa3.x);
        *(uint4*)(sm + 20480 + off) = make_uint4(pa0.y, pa1.y, pa2.y, pa3.y);
        *(uint4*)(sm + 40960 + off) = make_uint4(pb0.x, pb1.x, pb2.x, pb3.x);
        *(uint4*)(sm + 61440 + off) = make_uint4(pb0.y, pb1.y, pb2.y, pb3.y);
    }
    __syncthreads();

    const int lane = tid & 63;
    const int wid  = tid >> 6;
    const int wy = wid >> 1, wx = wid & 1;
    const int s0 = 80 * wy, t0 = 80 * wx;
    const int n16 = lane & 15, quad = lane >> 4, l7 = lane & 7;

    f32x4 acc[5][5];
    #pragma unroll
    for (int i = 0; i < 5; ++i)
        #pragma unroll
        for (int j = 0; j < 5; ++j) acc[i][j] = (f32x4){0.f, 0.f, 0.f, 0.f};

    #pragma unroll 1
    for (int ks = 0; ks < 2; ++ks) {
        const int sg = (4 * ks + quad) ^ l7;
        const char* abase = sm + (s0 + n16) * 128 + sg * 16;
        const char* bbase = sm + 40960 + (t0 + n16) * 128 + sg * 16;
        bf16x8 ah[5], al[5];
        #pragma unroll
        for (int i = 0; i < 5; ++i) {
            ah[i] = *(const bf16x8*)(abase + 2048 * i);
            al[i] = *(const bf16x8*)(abase + 20480 + 2048 * i);
        }
        #pragma unroll
        for (int j = 0; j < 5; ++j) {
            bf16x8 bh8 = *(const bf16x8*)(bbase + 2048 * j);
            bf16x8 bl8 = *(const bf16x8*)(bbase + 20480 + 2048 * j);
            #pragma unroll
            for (int i = 0; i < 5; ++i) {
                acc[i][j] = __builtin_amdgcn_mfma_f32_16x16x32_bf16(ah[i], bh8, acc[i][j], 0, 0, 0);
                acc[i][j] = __builtin_amdgcn_mfma_f32_16x16x32_bf16(al[i], bh8, acc[i][j], 0, 0, 0);
                acc[i][j] = __builtin_amdgcn_mfma_f32_16x16x32_bf16(ah[i], bl8, acc[i][j], 0, 0, 0);
            }
        }
    }
    __syncthreads();

    float* A1   = (float*)sm;
    float* A2   = A1 + SS;
    float* wred = A2 + SS;
    float* zred = wred + 8;

    if (tid < SS) { A1[tid] = 0.f; A2[tid] = 0.f; }

    float mloc = -1e30f;
    #pragma unroll
    for (int i = 0; i < 5; ++i)
        #pragma unroll
        for (int j = 0; j < 5; ++j)
            #pragma unroll
            for (int r = 0; r < 4; ++r) mloc = fmaxf(mloc, acc[i][j][r]);
    #pragma unroll
    for (int off = 32; off; off >>= 1) mloc = fmaxf(mloc, __shfl_xor(mloc, off, 64));
    if (lane == 0) wred[wid] = mloc;
    __syncthreads();
    const float m = fmaxf(fmaxf(wred[0], wred[1]), fmaxf(wred[2], wred[3]));

    float lsum = 0.f;
    #pragma unroll
    for (int i = 0; i < 5; ++i)
        #pragma unroll
        for (int j = 0; j < 5; ++j)
            #pragma unroll
            for (int r = 0; r < 4; ++r) {
                float e = __expf(acc[i][j][r] - m);
                acc[i][j][r] = e;
                lsum += e;
            }
    #pragma unroll
    for (int off = 32; off; off >>= 1) lsum += __shfl_xor(lsum, off, 64);
    if (lane == 0) wred[4 + wid] = lsum;

    #pragma unroll
    for (int i = 0; i < 5; ++i)
        #pragma unroll
        for (int r = 0; r < 4; ++r) {
            float rsv = 0.f;
            #pragma unroll
            for (int j = 0; j < 5; ++j) rsv += acc[i][j][r];
            rsv += __shfl_xor(rsv, 1, 64); rsv += __shfl_xor(rsv, 2, 64);
            rsv += __shfl_xor(rsv, 4, 64); rsv += __shfl_xor(rsv, 8, 64);
            if (n16 == 0) atomicAdd(&A1[s0 + 16 * i + 4 * quad + r], rsv);
        }
    #pragma unroll
    for (int j = 0; j < 5; ++j) {
        float csv = 0.f;
        #pragma unroll
        for (int i = 0; i < 5; ++i)
            #pragma unroll
            for (int r = 0; r < 4; ++r) csv += acc[i][j][r];
        csv += __shfl_xor(csv, 16, 64);
        csv += __shfl_xor(csv, 32, 64);
        if (quad == 0) atomicAdd(&A2[t0 + 16 * j + n16], csv);
    }
    __syncthreads();

    const float l = (wred[4] + wred[5]) + (wred[6] + wred[7]);
    if (tid == 0)
        out[(size_t)NB * NH * SS * DD + (size_t)bh * SS + qi] = m + __logf(l);

    const int d    = tid & 63;
    const int part = tid >> 6;
    const float* v1p = v1 + base;
    const float* v2p = v2 + base;
    float z = 0.f;
    #pragma unroll 4
    for (int s = part * 40; s < part * 40 + 40; ++s)
        z = fmaf(A1[s], v1p[s * DD + d], fmaf(A2[s], v2p[s * DD + d], z));
    zred[tid] = z;
    __syncthreads();
    if (tid < DD) {
        float zz = (zred[tid] + zred[tid + 64]) + (zred[tid + 128] + zred[tid + 192]);
        out[((size_t)bh * SS + qi) * DD + tid] = zz / l;
    }
}

extern "C" void kernel_launch(void* const* d_in, const int* in_sizes, int n_in,
                              void* d_out, int out_size, void* d_ws, size_t ws_size,
                              hipStream_t stream) {
    const float* q  = (const float*)d_in[0];
    const float* k1 = (const float*)d_in[1];
    const float* k2 = (const float*)d_in[2];
    const float* v1 = (const float*)d_in[3];
    const float* v2 = (const float*)d_in[4];
    float* out = (float*)d_out;

    const size_t REQ10 = (size_t)(409600 + 800 * 5120) * sizeof(float); // 18.0 MB
    const size_t REQ5  = (size_t)(409600 + 400 * 5120) * sizeof(float); // 9.83 MB (fit in R4)
    float* A1g = (float*)d_ws;
    float* A2p = A1g + 409600;
    if (ws_size >= REQ10) {
        tritt_p1<16><<<dim3(800), dim3(256), 0, stream>>>(q, k1, k2, A1g, A2p);
        tritt_p2<10><<<dim3(640), dim3(128), 0, stream>>>(v1, v2, A1g, A2p, out);
    } else if (ws_size >= REQ5) {
        tritt_p1<32><<<dim3(400), dim3(256), 0, stream>>>(q, k1, k2, A1g, A2p);
        tritt_p2<5><<<dim3(640), dim3(128), 0, stream>>>(v1, v2, A1g, A2p, out);
    } else {
        tritt_fb<<<dim3(NB * NH * SS), dim3(256), 0, stream>>>(q, k1, k2, v1, v2, out);
    }
}

// Round 8
// 134.058 us; speedup vs baseline: 1.1398x; 1.1398x over previous
//
#include <hip/hip_runtime.h>
#include <hip/hip_bf16.h>
#include <math.h>

#define NB 2
#define NH 8
#define BHN 16
#define SS 160
#define DD 64

typedef __attribute__((ext_vector_type(8))) short bf16x8;
typedef __attribute__((ext_vector_type(4))) float f32x4;

// pack 2 fp32 -> 2 bf16 (RNE) via v_cvt_pk_bf16_f32
__device__ __forceinline__ unsigned pk_rn(float a, float b) {
    __hip_bfloat162 h = __float22bfloat162_rn(make_float2(a, b));
    unsigned u; __builtin_memcpy(&u, &h, 4); return u;
}
// hi/lo split of a pair: hi = RNE bf16, lo = RNE bf16 of residual
__device__ __forceinline__ void split_rn(float a, float b, unsigned& hi, unsigned& lo) {
    hi = pk_rn(a, b);
    float f0 = __uint_as_float(hi << 16);
    float f1 = __uint_as_float(hi & 0xffff0000u);
    lo = pk_rn(a - f0, b - f1);
}

// ============================ PHASE 1 ============================
// Block = (bh, q-chunk 32, s-chunk SLEN). Per fixed s:
// scores[q32, t160] = (Q ⊙ k1[s,:]) x k2^T, 3-term bf16 hi/lo MFMA.
// k2 fragments (hi+lo, 80 VGPRs) are hoisted to registers, then the k2 LDS
// staging region is CLOBBERED by the k1 chunk + A1buf — the compiler cannot
// rematerialize the ds_reads, so frags stay register-resident (R6 showed it
// re-read 20 KB/wave/s-iter from LDS otherwise -> LDS-pipe bound).
// Outputs: A1g[bh][q][s] (exclusive slice), A2p[blk][32 q][160 t] partial.
template <int SLEN>
__global__ __launch_bounds__(256, 3) void tritt_p1(
    const float* __restrict__ q,  const float* __restrict__ k1,
    const float* __restrict__ k2, float* __restrict__ A1g,
    float* __restrict__ A2p)
{
    constexpr int NSC = SS / SLEN;
    __shared__ __align__(16) char sm[40960];        // 3 blocks/CU
    char*  k2hB  = sm;                              // phase 1: k2 hi
    char*  k2lB  = sm + 20480;                      // phase 1: k2 lo
    float* k1buf = (float*)sm;                      // phase 2 (clobbers k2h!)
    float* A1buf = (float*)(sm + SLEN * 256);       // phase 2: [SLEN s][32 q]

    const int tid = threadIdx.x;
    const int blk = blockIdx.x;
    const int bh  = blk / (5 * NSC);
    const int rem = blk % (5 * NSC);
    const int qc  = rem / NSC, sc = rem % NSC;
    const size_t base = (size_t)bh * SS * DD;

    // ---- k1 chunk global loads -> regs (stored to LDS after the hoist) ----
    constexpr int KL4 = SLEN * 16;                  // float4s in the chunk
    float4 kv[KL4 / 256];
    #pragma unroll
    for (int i = 0; i < KL4 / 256; ++i)
        kv[i] = ((const float4*)(k1 + base))[sc * KL4 + tid + 256 * i];

    // ---- Q rows (fp32 regs, pre-scaled by log2e): n16 -> q row, quad -> octet
    const int lane = tid & 63, wid = tid >> 6;
    const int mt = wid & 1, nh = wid >> 1;
    const int n16 = lane & 15, quad = lane >> 4;
    const float LOG2E = 1.4426950408889634f;
    const float* qrow = q + base + (size_t)(qc * 32 + mt * 16 + n16) * DD + quad * 8;
    float Qf[2][8];
    #pragma unroll
    for (int ks = 0; ks < 2; ++ks) {
        float4 a = *(const float4*)(qrow + 32 * ks);
        float4 b = *(const float4*)(qrow + 32 * ks + 4);
        Qf[ks][0] = a.x * LOG2E; Qf[ks][1] = a.y * LOG2E;
        Qf[ks][2] = a.z * LOG2E; Qf[ks][3] = a.w * LOG2E;
        Qf[ks][4] = b.x * LOG2E; Qf[ks][5] = b.y * LOG2E;
        Qf[ks][6] = b.z * LOG2E; Qf[ks][7] = b.w * LOG2E;
    }

    // ---- stage k2 (all 160 t) as hi/lo bf16, 16B-block swizzled by t&7 ----
    const float4* k2f = (const float4*)(k2 + base);
    #pragma unroll
    for (int it = 0; it < 5; ++it) {
        int f = tid + 256 * it;                     // t = f>>3, 16B-block o = f&7
        int t = f >> 3, o = f & 7;
        float4 x0 = k2f[t * 16 + 2 * o];
        float4 x1 = k2f[t * 16 + 2 * o + 1];
        unsigned h0, l0, h1, l1, h2, l2, h3, l3;
        split_rn(x0.x, x0.y, h0, l0);
        split_rn(x0.z, x0.w, h1, l1);
        split_rn(x1.x, x1.y, h2, l2);
        split_rn(x1.z, x1.w, h3, l3);
        int off = t * 128 + ((o ^ (t & 7)) * 16);
        *(uint4*)(k2hB + off) = make_uint4(h0, h1, h2, h3);
        *(uint4*)(k2lB + off) = make_uint4(l0, l1, l2, l3);
    }
    __syncthreads();                                // #1: staging visible

    // ---- hoist ALL k2 fragments (hi+lo) into registers ----
    const int trow = nh * 80 + n16;
    const int swz  = n16 & 7;
    const char* bb0 = k2hB + trow * 128 + ((quad) ^ swz) * 16;
    const char* bb1 = k2hB + trow * 128 + ((4 + quad) ^ swz) * 16;
    const char* lb0 = k2lB + trow * 128 + ((quad) ^ swz) * 16;
    const char* lb1 = k2lB + trow * 128 + ((4 + quad) ^ swz) * 16;
    bf16x8 BH0[5], BH1[5], BL0[5], BL1[5];
    #pragma unroll
    for (int j = 0; j < 5; ++j) {
        BH0[j] = *(const bf16x8*)(bb0 + 2048 * j);
        BH1[j] = *(const bf16x8*)(bb1 + 2048 * j);
        BL0[j] = *(const bf16x8*)(lb0 + 2048 * j);
        BL1[j] = *(const bf16x8*)(lb1 + 2048 * j);
    }
    __syncthreads();                                // #2: all waves done hoisting

    // ---- clobber: k1 chunk + A1buf over the dead k2 staging ----
    #pragma unroll
    for (int i = 0; i < KL4 / 256; ++i)
        ((float4*)k1buf)[tid + 256 * i] = kv[i];
    if (tid < SLEN * 8)
        ((float4*)A1buf)[tid] = make_float4(0.f, 0.f, 0.f, 0.f);
    __syncthreads();                                // #3

    f32x4 A2acc[5];
    #pragma unroll
    for (int j = 0; j < 5; ++j) A2acc[j] = (f32x4){0.f, 0.f, 0.f, 0.f};
    const f32x4 zero4 = (f32x4){0.f, 0.f, 0.f, 0.f};

    // ---- s-loop: build A = Q ⊙ k1[s,:], 30 MFMAs, exp2, accumulate ----
    #pragma unroll 1
    for (int s = 0; s < SLEN; ++s) {
        const float* k1row = k1buf + s * 64 + quad * 8;
        uint4 AH[2], AL[2];
        #pragma unroll
        for (int ks = 0; ks < 2; ++ks) {
            float4 a = *(const float4*)(k1row + 32 * ks);
            float4 b = *(const float4*)(k1row + 32 * ks + 4);
            split_rn(Qf[ks][0] * a.x, Qf[ks][1] * a.y, AH[ks].x, AL[ks].x);
            split_rn(Qf[ks][2] * a.z, Qf[ks][3] * a.w, AH[ks].y, AL[ks].y);
            split_rn(Qf[ks][4] * b.x, Qf[ks][5] * b.y, AH[ks].z, AL[ks].z);
            split_rn(Qf[ks][6] * b.z, Qf[ks][7] * b.w, AH[ks].w, AL[ks].w);
        }
        bf16x8 ah0 = *(bf16x8*)&AH[0], al0 = *(bf16x8*)&AL[0];
        bf16x8 ah1 = *(bf16x8*)&AH[1], al1 = *(bf16x8*)&AL[1];

        float rsum[4] = {0.f, 0.f, 0.f, 0.f};
        #pragma unroll
        for (int j = 0; j < 5; ++j) {
            f32x4 a = __builtin_amdgcn_mfma_f32_16x16x32_bf16(ah0, BH0[j], zero4, 0, 0, 0);
            a = __builtin_amdgcn_mfma_f32_16x16x32_bf16(al0, BH0[j], a, 0, 0, 0);
            a = __builtin_amdgcn_mfma_f32_16x16x32_bf16(ah0, BL0[j], a, 0, 0, 0);
            a = __builtin_amdgcn_mfma_f32_16x16x32_bf16(ah1, BH1[j], a, 0, 0, 0);
            a = __builtin_amdgcn_mfma_f32_16x16x32_bf16(al1, BH1[j], a, 0, 0, 0);
            a = __builtin_amdgcn_mfma_f32_16x16x32_bf16(ah1, BL1[j], a, 0, 0, 0);
            #pragma unroll
            for (int r = 0; r < 4; ++r) {
                float e = exp2f(a[r]);
                A2acc[j][r] += e;
                rsum[r] += e;
            }
        }
        #pragma unroll
        for (int r = 0; r < 4; ++r) {
            float v = rsum[r];
            v += __shfl_xor(v, 1, 64); v += __shfl_xor(v, 2, 64);
            v += __shfl_xor(v, 4, 64); v += __shfl_xor(v, 8, 64);
            if (n16 == 0)
                atomicAdd(&A1buf[s * 32 + mt * 16 + quad * 4 + r], v);
        }
    }
    __syncthreads();                                // #4: A1buf complete

    // ---- write A1 slice (exclusive) ----
    {
        float* dst = A1g + (size_t)bh * 25600 + sc * SLEN;
        if (SLEN == 16) {
            int qi = tid >> 3, s2 = (tid & 7) * 2;
            float2 w = make_float2(A1buf[s2 * 32 + qi], A1buf[(s2 + 1) * 32 + qi]);
            *(float2*)(dst + (size_t)(qc * 32 + qi) * SS + s2) = w;
        } else {
            int qi = tid >> 3, s4 = (tid & 7) * 4;
            float4 w = make_float4(A1buf[s4 * 32 + qi], A1buf[(s4 + 1) * 32 + qi],
                                   A1buf[(s4 + 2) * 32 + qi], A1buf[(s4 + 3) * 32 + qi]);
            *(float4*)(dst + (size_t)(qc * 32 + qi) * SS + s4) = w;
        }
    }
    // ---- write A2 partial (exclusive, plain stores) ----
    {
        float* pb = A2p + (size_t)blk * 5120;
        #pragma unroll
        for (int j = 0; j < 5; ++j)
            #pragma unroll
            for (int r = 0; r < 4; ++r)
                pb[(mt * 16 + quad * 4 + r) * SS + nh * 80 + j * 16 + n16] = A2acc[j][r];
    }
}

// ============================ PHASE 2 ============================
// One query per wave (2560 waves). Reduce the NSC A2 partials, stage both
// marginal rows in per-wave LDS, GEMV against v1/v2 once, l from A1 row.
template <int NSC>
__global__ __launch_bounds__(256) void tritt_p2(
    const float* __restrict__ v1, const float* __restrict__ v2,
    const float* __restrict__ A1g, const float* __restrict__ A2p,
    float* __restrict__ out)
{
    __shared__ float rbuf[4][2][SS];
    const int tid = threadIdx.x, lane = tid & 63, wid = tid >> 6;
    const int g  = blockIdx.x * 4 + wid;            // 0..2559
    const int bh = g / SS, qr = g % SS;
    const int qc = qr >> 5, ql = qr & 31;
    const size_t base = (size_t)bh * SS * DD;

    const float* a1r = A1g + (size_t)bh * 25600 + (size_t)qr * SS;
    float a10 = a1r[lane], a11 = a1r[lane + 64];
    float a12 = (lane < 32) ? a1r[lane + 128] : 0.f;

    float a20 = 0.f, a21 = 0.f, a22 = 0.f;
    const float* pb = A2p + (size_t)((bh * 5 + qc) * NSC) * 5120 + (size_t)ql * SS;
    #pragma unroll
    for (int p = 0; p < NSC; ++p) {
        const float* r = pb + (size_t)p * 5120;
        a20 += r[lane]; a21 += r[lane + 64];
        if (lane < 32) a22 += r[lane + 128];
    }
    rbuf[wid][0][lane] = a10; rbuf[wid][0][lane + 64] = a11;
    rbuf[wid][1][lane] = a20; rbuf[wid][1][lane + 64] = a21;
    if (lane < 32) { rbuf[wid][0][lane + 128] = a12; rbuf[wid][1][lane + 128] = a22; }

    float l = a10 + a11 + a12;
    #pragma unroll
    for (int off = 32; off; off >>= 1) l += __shfl_xor(l, off, 64);

    const float* A1s = rbuf[wid][0];
    const float* A2s = rbuf[wid][1];
    const float* v1p = v1 + base;
    const float* v2p = v2 + base;
    float z0 = 0.f, z1 = 0.f;
    #pragma unroll 8
    for (int s = 0; s < SS; s += 2) {
        z0 = fmaf(A1s[s],     v1p[s * DD + lane],       z0);
        z1 = fmaf(A1s[s + 1], v1p[(s + 1) * DD + lane], z1);
    }
    #pragma unroll 8
    for (int t = 0; t < SS; t += 2) {
        z0 = fmaf(A2s[t],     v2p[t * DD + lane],       z0);
        z1 = fmaf(A2s[t + 1], v2p[(t + 1) * DD + lane], z1);
    }
    out[base + (size_t)qr * DD + lane] = (z0 + z1) / l;
    if (lane == 0) out[(size_t)BHN * SS * DD + g] = __logf(l);
}

// ==================== FALLBACK (proven R2, ~74us) ====================
__device__ __forceinline__ uint2 splitpair_fb(float a0, float a1) {
    unsigned u0 = __float_as_uint(a0), u1 = __float_as_uint(a1);
    unsigned hi = (u0 >> 16) | (u1 & 0xffff0000u);
    float r0 = a0 - __uint_as_float(u0 & 0xffff0000u);
    float r1 = a1 - __uint_as_float(u1 & 0xffff0000u);
    unsigned v0 = __float_as_uint(r0), v1 = __float_as_uint(r1);
    unsigned lo = (v0 >> 16) | (v1 & 0xffff0000u);
    return make_uint2(hi, lo);
}

__global__ __launch_bounds__(256, 2) void tritt_fb(
    const float* __restrict__ q,  const float* __restrict__ k1,
    const float* __restrict__ k2, const float* __restrict__ v1,
    const float* __restrict__ v2, float* __restrict__ out)
{
    __shared__ __align__(16) char sm[81920];
    const int tid = threadIdx.x;
    const int blk = blockIdx.x;
    const int bh  = blk / SS;
    const int qi  = blk % SS;
    const size_t base = (size_t)bh * SS * DD;

    const float4* k1f = (const float4*)(k1 + base);
    const float4* k2f = (const float4*)(k2 + base);
    const float4* qf  = (const float4*)(q + base + (size_t)qi * DD);

    #pragma unroll
    for (int it = 0; it < 5; ++it) {
        int f = tid + 256 * it;
        int s = f >> 3, g = f & 7;
        int fg = s * 16 + g * 2;
        float4 x0 = k1f[fg], x1 = k1f[fg + 1];
        float4 y0 = k2f[fg], y1 = k2f[fg + 1];
        float4 q0 = qf[g * 2], q1 = qf[g * 2 + 1];
        uint2 pa0 = splitpair_fb(x0.x * q0.x, x0.y * q0.y);
        uint2 pa1 = splitpair_fb(x0.z * q0.z, x0.w * q0.w);
        uint2 pa2 = splitpair_fb(x1.x * q1.x, x1.y * q1.y);
        uint2 pa3 = splitpair_fb(x1.z * q1.z, x1.w * q1.w);
        uint2 pb0 = splitpair_fb(y0.x, y0.y);
        uint2 pb1 = splitpair_fb(y0.z, y0.w);
        uint2 pb2 = splitpair_fb(y1.x, y1.y);
        uint2 pb3 = splitpair_fb(y1.z, y1.w);
        int off = s * 128 + ((g ^ (s & 7)) * 16);
        *(uint4*)(sm + off)         = make_uint4(pa0.x, pa1.x, pa2.x, pa3.x);
        *(uint4*)(sm + 20480 + off) = make_uint4(pa0.y, pa1.y, pa2.y, pa3.y);
        *(uint4*)(sm + 40960 + off) = make_uint4(pb0.x, pb1.x, pb2.x, pb3.x);
        *(uint4*)(sm + 61440 + off) = make_uint4(pb0.y, pb1.y, pb2.y, pb3.y);
    }
    __syncthreads();

    const int lane = tid & 63;
    const int wid  = tid >> 6;
    const int wy = wid >> 1, wx = wid & 1;
    const int s0 = 80 * wy, t0 = 80 * wx;
    const int n16 = lane & 15, quad = lane >> 4, l7 = lane & 7;

    f32x4 acc[5][5];
    #pragma unroll
    for (int i = 0; i < 5; ++i)
        #pragma unroll
        for (int j = 0; j < 5; ++j) acc[i][j] = (f32x4){0.f, 0.f, 0.f, 0.f};

    #pragma unroll 1
    for (int ks = 0; ks < 2; ++ks) {
        const int sg = (4 * ks + quad) ^ l7;
        const char* abase = sm + (s0 + n16) * 128 + sg * 16;
        const char* bbase = sm + 40960 + (t0 + n16) * 128 + sg * 16;
        bf16x8 ah[5], al[5];
        #pragma unroll
        for (int i = 0; i < 5; ++i) {
            ah[i] = *(const bf16x8*)(abase + 2048 * i);
            al[i] = *(const bf16x8*)(abase + 20480 + 2048 * i);
        }
        #pragma unroll
        for (int j = 0; j < 5; ++j) {
            bf16x8 bh8 = *(const bf16x8*)(bbase + 2048 * j);
            bf16x8 bl8 = *(const bf16x8*)(bbase + 20480 + 2048 * j);
            #pragma unroll
            for (int i = 0; i < 5; ++i) {
                acc[i][j] = __builtin_amdgcn_mfma_f32_16x16x32_bf16(ah[i], bh8, acc[i][j], 0, 0, 0);
                acc[i][j] = __builtin_amdgcn_mfma_f32_16x16x32_bf16(al[i], bh8, acc[i][j], 0, 0, 0);
                acc[i][j] = __builtin_amdgcn_mfma_f32_16x16x32_bf16(ah[i], bl8, acc[i][j], 0, 0, 0);
            }
        }
    }
    __syncthreads();

    float* A1   = (float*)sm;
    float* A2   = A1 + SS;
    float* wred = A2 + SS;
    float* zred = wred + 8;

    if (tid < SS) { A1[tid] = 0.f; A2[tid] = 0.f; }

    float mloc = -1e30f;
    #pragma unroll
    for (int i = 0; i < 5; ++i)
        #pragma unroll
        for (int j = 0; j < 5; ++j)
            #pragma unroll
            for (int r = 0; r < 4; ++r) mloc = fmaxf(mloc, acc[i][j][r]);
    #pragma unroll
    for (int off = 32; off; off >>= 1) mloc = fmaxf(mloc, __shfl_xor(mloc, off, 64));
    if (lane == 0) wred[wid] = mloc;
    __syncthreads();
    const float m = fmaxf(fmaxf(wred[0], wred[1]), fmaxf(wred[2], wred[3]));

    float lsum = 0.f;
    #pragma unroll
    for (int i = 0; i < 5; ++i)
        #pragma unroll
        for (int j = 0; j < 5; ++j)
            #pragma unroll
            for (int r = 0; r < 4; ++r) {
                float e = __expf(acc[i][j][r] - m);
                acc[i][j][r] = e;
                lsum += e;
            }
    #pragma unroll
    for (int off = 32; off; off >>= 1) lsum += __shfl_xor(lsum, off, 64);
    if (lane == 0) wred[4 + wid] = lsum;

    #pragma unroll
    for (int i = 0; i < 5; ++i)
        #pragma unroll
        for (int r = 0; r < 4; ++r) {
            float rsv = 0.f;
            #pragma unroll
            for (int j = 0; j < 5; ++j) rsv += acc[i][j][r];
            rsv += __shfl_xor(rsv, 1, 64); rsv += __shfl_xor(rsv, 2, 64);
            rsv += __shfl_xor(rsv, 4, 64); rsv += __shfl_xor(rsv, 8, 64);
            if (n16 == 0) atomicAdd(&A1[s0 + 16 * i + 4 * quad + r], rsv);
        }
    #pragma unroll
    for (int j = 0; j < 5; ++j) {
        float csv = 0.f;
        #pragma unroll
        for (int i = 0; i < 5; ++i)
            #pragma unroll
            for (int r = 0; r < 4; ++r) csv += acc[i][j][r];
        csv += __shfl_xor(csv, 16, 64);
        csv += __shfl_xor(csv, 32, 64);
        if (quad == 0) atomicAdd(&A2[t0 + 16 * j + n16], csv);
    }
    __syncthreads();

    const float l = (wred[4] + wred[5]) + (wred[6] + wred[7]);
    if (tid == 0)
        out[(size_t)NB * NH * SS * DD + (size_t)bh * SS + qi] = m + __logf(l);

    const int d    = tid & 63;
    const int part = tid >> 6;
    const float* v1p = v1 + base;
    const float* v2p = v2 + base;
    float z = 0.f;
    #pragma unroll 4
    for (int s = part * 40; s < part * 40 + 40; ++s)
        z = fmaf(A1[s], v1p[s * DD + d], fmaf(A2[s], v2p[s * DD + d], z));
    zred[tid] = z;
    __syncthreads();
    if (tid < DD) {
        float zz = (zred[tid] + zred[tid + 64]) + (zred[tid + 128] + zred[tid + 192]);
        out[((size_t)bh * SS + qi) * DD + tid] = zz / l;
    }
}

extern "C" void kernel_launch(void* const* d_in, const int* in_sizes, int n_in,
                              void* d_out, int out_size, void* d_ws, size_t ws_size,
                              hipStream_t stream) {
    const float* q  = (const float*)d_in[0];
    const float* k1 = (const float*)d_in[1];
    const float* k2 = (const float*)d_in[2];
    const float* v1 = (const float*)d_in[3];
    const float* v2 = (const float*)d_in[4];
    float* out = (float*)d_out;

    const size_t REQ10 = (size_t)(409600 + 800 * 5120) * sizeof(float); // 18.02 MB (proven fit)
    const size_t REQ5  = (size_t)(409600 + 400 * 5120) * sizeof(float); // 9.83 MB (proven fit)
    float* A1g = (float*)d_ws;
    float* A2p = A1g + 409600;
    if (ws_size >= REQ10) {
        tritt_p1<16><<<dim3(800), dim3(256), 0, stream>>>(q, k1, k2, A1g, A2p);
        tritt_p2<10><<<dim3(640), dim3(256), 0, stream>>>(v1, v2, A1g, A2p, out);
    } else if (ws_size >= REQ5) {
        tritt_p1<32><<<dim3(400), dim3(256), 0, stream>>>(q, k1, k2, A1g, A2p);
        tritt_p2<5><<<dim3(640), dim3(256), 0, stream>>>(v1, v2, A1g, A2p, out);
    } else {
        tritt_fb<<<dim3(NB * NH * SS), dim3(256), 0, stream>>>(q, k1, k2, v1, v2, out);
    }
}